// Round 13
// baseline (135.393 us; speedup 1.0000x reference)
//
#include <hip/hip_runtime.h>
#include <hip/hip_bf16.h>

typedef __hip_bfloat16 bf16;
typedef __attribute__((ext_vector_type(4))) float f32x4;
typedef __attribute__((ext_vector_type(8))) short bf16x8;

constexpr int kB  = 2;
constexpr int kC  = 64;
constexpr int kCi = 16;
constexpr int kN  = 6400;   // 80*80
constexpr int QT  = 16;     // queries per block
constexpr int KT  = 256;    // keys per chunk (8 waves x 32 keys, full-K MFMAs)
constexpr int NCH = kN / KT; // 25

// proj scratch layouts (all bf16):
//   theta: [b][n][ci]                       rows 32 B
//   phi:   [b][n][ci + 8B pad]              rows 48 B (pad unread)
//   gx/gb: 32-key supergroups, 1024 B: row ci (64 B) holds 4 content slots;
//          content slot g stored at PHYSICAL slot (g + (ci>>1)) & 3
//          (bank-conflict swizzle, R12 post-mortem: linear slots = 8-way)
constexpr int THB = 32;
constexpr int PHB = 48;
constexpr int SGB = 1024;                  // bytes per 32-key supergroup
constexpr int PH_CH = KT * PHB;            // 12288  (chunk stride, phi)
constexpr int G_CH  = (KT / 32) * SGB;     // 8192   (chunk stride, g)
// per-wave slice: ph 1536 | gx 1024 | gb 1024 = 3584 B
constexpr int WSL  = 3584;
constexpr int W_PH = 1536;
constexpr int W_GX = 1024;
constexpr int BUF_BYTES = 8 * WSL;         // 28672
// LDS: 2*28672 + 512 theta = 57856 -> 2 blocks/CU

#define EPS_BN 1e-5f

__device__ __forceinline__ float b2f(bf16 v) { return __bfloat162float(v); }
__device__ __forceinline__ unsigned short f2bf(float f) {
    bf16 h = __float2bfloat16(f);
    return *reinterpret_cast<unsigned short*>(&h);
}
__device__ __forceinline__ float ldin(const void* p, size_t i, int bf) {
    return bf ? __bfloat162float(((const bf16*)p)[i]) : ((const float*)p)[i];
}
__device__ __forceinline__ void stout(void* p, size_t i, float v, int bf) {
    if (bf) ((bf16*)p)[i] = __float2bfloat16(v);
    else    ((float*)p)[i] = v;
}
__device__ __forceinline__ void g2lds16(const void* gsrc, void* ldst) {
    __builtin_amdgcn_global_load_lds(
        (const __attribute__((address_space(1))) void*)gsrc,
        (__attribute__((address_space(3))) void*)ldst,
        16, 0, 0);
}
__device__ __forceinline__ unsigned pack2(unsigned short a, unsigned short b) {
    return (unsigned)a | ((unsigned)b << 16);
}
// count "wild" bf16 exponents (e<64 || e>191) in 8 halfwords of a uint4
__device__ __forceinline__ int wild8(uint4 v) {
    int wc = 0;
    unsigned u[4] = {v.x, v.y, v.z, v.w};
#pragma unroll
    for (int i = 0; i < 4; ++i) {
        int e0 = (u[i] >> 7)  & 0xFF;
        int e1 = (u[i] >> 23) & 0xFF;
        wc += (e0 < 64 || e0 > 191);
        wc += (e1 < 64 || e1 > 191);
    }
    return wc;
}

// ---------------------------------------------------------------------------
// Kernel 1: projections -> bf16 in MFMA-ready layouts. Self-detects dtype.
// Grid = 800 blocks; block = (sec, b, 64-pixel tile).
// g-layout: supergroup row ci: content key r=4*gg+k (gg 0..7, k 0..3),
//   content slot s=gg&3 -> physical byte
//   ci*64 + (((gg&3)+(ci>>1))&3)*16 + (gg>>2)*8 + k*2   [swizzled]
// ---------------------------------------------------------------------------
__global__ __launch_bounds__(256)
void proj_kernel(const void* __restrict__ bfimg, const void* __restrict__ x,
                 const void* __restrict__ w_theta, const void* __restrict__ b_theta,
                 const void* __restrict__ w_phi,   const void* __restrict__ b_phi,
                 const void* __restrict__ w_g,     const void* __restrict__ b_g,
                 const void* __restrict__ w_gbf,   const void* __restrict__ b_gbf,
                 char* __restrict__ th_p, char* __restrict__ ph_p,
                 char* __restrict__ gx_p, char* __restrict__ gb_p)
{
    __shared__ float w_s[kCi][kC];                 // 4 KB
    __shared__ float b_s[kCi];
    __shared__ __align__(16) char out_s[64 * PHB]; // 3072 B (>= 2048 g-bytes)
    __shared__ int dred[4];

    const int tid = threadIdx.x;
    const int wv  = tid >> 6;
    const int l   = tid & 63;

    // ---- dtype self-detect ----
    int wc = wild8(*(const uint4*)((const char*)bfimg + tid * 16));
#pragma unroll
    for (int off = 32; off > 0; off >>= 1) wc += __shfl_down(wc, off);
    if (l == 0) dred[wv] = wc;
    __syncthreads();
    const int bf = ((dred[0] + dred[1] + dred[2] + dred[3]) * 8 < 2048) ? 1 : 0;

    const int bid = blockIdx.x;        // [0, 800)
    const int sec = bid / 200;         // 0..3
    const int r   = bid % 200;
    const int b   = r / 100;
    const int t64 = r % 100;
    const int n0  = t64 * 64;

    const void *src, *w, *bias;
    if (sec == 0)      { src = bfimg; w = w_theta; bias = b_theta; }
    else if (sec == 1) { src = bfimg; w = w_phi;   bias = b_phi;   }
    else if (sec == 2) { src = x;     w = w_g;     bias = b_g;     }
    else               { src = bfimg; w = w_gbf;   bias = b_gbf;   }

    for (int i = tid; i < kCi * kC; i += 256)
        w_s[i >> 6][i & 63] = ldin(w, i, bf);
    if (tid < kCi) b_s[tid] = ldin(bias, tid, bf);
    __syncthreads();

    const int px = tid & 63;
    const int cg = tid >> 6;           // ci quad
    const int n  = n0 + px;

    float a0 = b_s[cg * 4 + 0], a1 = b_s[cg * 4 + 1];
    float a2 = b_s[cg * 4 + 2], a3 = b_s[cg * 4 + 3];
    const size_t ibase = (size_t)b * kC * kN + n;
#pragma unroll 8
    for (int ch = 0; ch < kC; ++ch) {
        float v = ldin(src, ibase + (size_t)ch * kN, bf);
        a0 = fmaf(w_s[cg * 4 + 0][ch], v, a0);
        a1 = fmaf(w_s[cg * 4 + 1][ch], v, a1);
        a2 = fmaf(w_s[cg * 4 + 2][ch], v, a2);
        a3 = fmaf(w_s[cg * 4 + 3][ch], v, a3);
    }

    if (sec < 2) {
        const int RB = sec ? PHB : THB;
        uint2 v; v.x = pack2(f2bf(a0), f2bf(a1)); v.y = pack2(f2bf(a2), f2bf(a3));
        *(uint2*)(out_s + px * RB + cg * 8) = v;
        __syncthreads();
        const int bytes = 64 * RB;
        char* dst = (sec ? ph_p : th_p) + ((size_t)b * kN + n0) * RB;
        for (int i = tid * 16; i < bytes; i += 256 * 16)
            *(uint4*)(dst + i) = *(const uint4*)(out_s + i);
    } else {
        // swizzled supergroup layout: this thread's 4 keys are r=4*gg+k
        const int k  = px & 3;
        const int Gl = px >> 2;            // 0..15 local 4-key group
        const int sg = Gl >> 3;            // 0/1 local supergroup
        const int gg = Gl & 7;
        const int inner = (gg >> 2) * 8 + k * 2;
        const int s_c   = gg & 3;          // content slot
#pragma unroll
        for (int j = 0; j < 4; ++j) {
            const int ci = cg * 4 + j;
            const int s_p = (s_c + (ci >> 1)) & 3;    // physical slot (swizzle)
            const float av = (j == 0) ? a0 : (j == 1) ? a1 : (j == 2) ? a2 : a3;
            *(unsigned short*)(out_s + sg * SGB + ci * 64 + s_p * 16 + inner) = f2bf(av);
        }
        __syncthreads();
        const int bytes = 2 * SGB;         // 2048
        char* dst = (sec == 2 ? gx_p : gb_p)
                  + (size_t)b * (kN / 32) * SGB + (size_t)(n0 >> 5) * SGB;
        for (int i = tid * 16; i < bytes; i += 256 * 16)
            *(uint4*)(dst + i) = *(const uint4*)(out_s + i);
    }
}

// ---------------------------------------------------------------------------
// Kernel 2: MFMA attention, barrier-free, 8 waves x 32 keys, KT=256.
// Identical to R12 except the PV read uses the swizzled slot address
// (((g + (h>>1)) & 3) << 4): per quarter-wave the 16 lanes now cover all 8
// bank-quads twice (2-way = free, m136) instead of 2 quads x8 (8-way).
// ---------------------------------------------------------------------------
__global__ __launch_bounds__(512, 4)
void attn_kernel(const char* __restrict__ th_p, const char* __restrict__ ph_p,
                 const char* __restrict__ gx_p, const char* __restrict__ gb_p,
                 const void* __restrict__ bfimg, const void* __restrict__ x,
                 const void* __restrict__ w_W,  const void* __restrict__ b_W,
                 const void* __restrict__ gamma, const void* __restrict__ beta,
                 const void* __restrict__ mean,  const void* __restrict__ var,
                 void* __restrict__ out)
{
    __shared__ __align__(16) char smem[2 * BUF_BYTES + 512];  // 57856 B

    const int tid = threadIdx.x;
    const int w   = tid >> 6;          // 0..7
    const int l   = tid & 63;
    const int g   = l >> 4;            // 0..3
    const int h   = l & 15;
    const int b   = blockIdx.x / (kN / QT);
    const int q0  = (blockIdx.x % (kN / QT)) * QT;

    // ---- dtype self-detect sample (reduced after main loop) ----
    int wc = wild8(*(const uint4*)((const char*)bfimg + tid * 16));

    // ---- wave-private DMA plan: instr R, slice byte ofs = R*1024 + l*16
    //      regions: ph [0,1536) | gx [1536,2560) | gb [2560,3584)
    const char* srcp[4]; int strv[4]; int dofs[4];
#pragma unroll
    for (int R = 0; R < 4; ++R) {
        int ofs = R * 1024 + l * 16;
        if (ofs < W_PH) {
            srcp[R] = ph_p + (size_t)b * kN * PHB + (size_t)w * W_PH + ofs;
            strv[R] = PH_CH;
        } else if (ofs < W_PH + W_GX) {
            srcp[R] = gx_p + (size_t)b * (kN / 32) * SGB + (size_t)w * SGB + (ofs - W_PH);
            strv[R] = G_CH;
        } else {
            srcp[R] = gb_p + (size_t)b * (kN / 32) * SGB + (size_t)w * SGB + (ofs - W_PH - W_GX);
            strv[R] = G_CH;
        }
        dofs[R] = w * WSL + ofs;
    }
#define STAGE(it, sel)                                                      \
    {                                                                       \
        g2lds16(srcp[0] + (size_t)(it) * strv[0], smem + (sel) * BUF_BYTES + dofs[0]); \
        g2lds16(srcp[1] + (size_t)(it) * strv[1], smem + (sel) * BUF_BYTES + dofs[1]); \
        g2lds16(srcp[2] + (size_t)(it) * strv[2], smem + (sel) * BUF_BYTES + dofs[2]); \
        if (l < 32)                                                         \
            g2lds16(srcp[3] + (size_t)(it) * strv[3], smem + (sel) * BUF_BYTES + dofs[3]); \
    }

    // ---- prologue: chunk 0 + theta tile (512 B, first 256 threads) ----
    STAGE(0, 0);
    if (tid < 256)
        ((unsigned short*)(smem + 2 * BUF_BYTES))[tid] =
            *(const unsigned short*)(th_p + ((size_t)b * kN + q0) * THB + tid * 2);
    __syncthreads();                      // theta visible + stage 0 drained

    bf16x8 bq;
#pragma unroll
    for (int j = 0; j < 8; ++j) bq[j] = 0;
    if (g < 2) bq = *(const bf16x8*)(smem + 2 * BUF_BYTES + h * THB + g * 16);

    // swizzled PV slot offset for this lane (constant across chunks)
    const int pv_off = h * 64 + (((g + (h >> 1)) & 3) << 4);

    const f32x4 z4 = {0.f, 0.f, 0.f, 0.f};
    f32x4 accx = z4, accb = z4;
    float lsum = 0.f;

    auto compute = [&](int it) {
        const char* wbuf = smem + (it & 1) * BUF_BYTES + w * WSL;

        // --- QK^T: A = phi rows (wave's two 16-key tiles) ---
        bf16x8 a0, a1;
#pragma unroll
        for (int j = 0; j < 8; ++j) { a0[j] = 0; a1[j] = 0; }
        if (g < 2) {
            a0 = *(const bf16x8*)(wbuf + h * PHB + g * 16);
            a1 = *(const bf16x8*)(wbuf + (16 + h) * PHB + g * 16);
        }
        f32x4 s0 = __builtin_amdgcn_mfma_f32_16x16x32_bf16(a0, bq, z4, 0, 0, 0);
        f32x4 s1 = __builtin_amdgcn_mfma_f32_16x16x32_bf16(a1, bq, z4, 0, 0, 0);

        // --- softmax numerators (exact, no max-sub) ---
        float p0 = __expf(s0[0]), p1 = __expf(s0[1]), p2 = __expf(s0[2]), p3 = __expf(s0[3]);
        float p4 = __expf(s1[0]), p5 = __expf(s1[1]), p6 = __expf(s1[2]), p7 = __expf(s1[3]);
        lsum += (p0 + p1) + (p2 + p3) + (p4 + p5) + (p6 + p7);

        union { unsigned short u[8]; bf16x8 v; } pa;
        pa.u[0] = f2bf(p0); pa.u[1] = f2bf(p1); pa.u[2] = f2bf(p2); pa.u[3] = f2bf(p3);
        pa.u[4] = f2bf(p4); pa.u[5] = f2bf(p5); pa.u[6] = f2bf(p6); pa.u[7] = f2bf(p7);

        // --- PV: one b128 per branch, swizzled slot (2-way banks) ---
        bf16x8 bx = *(const bf16x8*)(wbuf + W_PH + pv_off);
        bf16x8 bb = *(const bf16x8*)(wbuf + W_PH + W_GX + pv_off);

        accx = __builtin_amdgcn_mfma_f32_16x16x32_bf16(pa.v, bx, accx, 0, 0, 0);
        accb = __builtin_amdgcn_mfma_f32_16x16x32_bf16(pa.v, bb, accb, 0, 0, 0);
    };

    // ---- barrier-free main loop: counted vmcnt, wave-private slices ----
    for (int it = 0; it < NCH - 1; ++it) {
        STAGE(it + 1, (it + 1) & 1);
        asm volatile("s_waitcnt vmcnt(4)" ::: "memory");   // stage(it) done
        __builtin_amdgcn_sched_barrier(0);
        compute(it);
    }
    asm volatile("s_waitcnt vmcnt(0)" ::: "memory");       // last chunk done
    __builtin_amdgcn_sched_barrier(0);
    compute(NCH - 1);
#undef STAGE

    // ---- reduce l across lane-groups: lanes 0-15 hold q=l totals ----
    lsum += __shfl_down(lsum, 16);
    lsum += __shfl_down(lsum, 32);
#pragma unroll
    for (int off = 32; off > 0; off >>= 1) wc += __shfl_down(wc, off);

    // FENCE before LDS reuse: all waves past their last buffer reads.
    __syncthreads();

    // buffers dead; reuse LDS
    float* ys = (float*)smem;            // [8w][2br][16q][16ci] 16384 B
    float* ls = (float*)(smem + 16384);  // [8w][16q]            512 B
    float* y2 = (float*)(smem + 16896);  // [16q][33]            2112 B
    int*   wd = (int*)(smem + 19008);    // [8w]                 32 B
    if (l < 16) ls[w * 16 + l] = lsum;
    if (l == 0) wd[w] = wc;
#pragma unroll
    for (int r = 0; r < 4; ++r) {
        int q = g * 4 + r;               // verified D layout: row=(lane>>4)*4+r
        ys[(((w * 2 + 0) * 16) + q) * 16 + h] = accx[r];
        ys[(((w * 2 + 1) * 16) + q) * 16 + h] = accb[r];
    }
    __syncthreads();

    const int bf = ((wd[0] + wd[1] + wd[2] + wd[3] +
                     wd[4] + wd[5] + wd[6] + wd[7]) * 8 < 4096) ? 1 : 0;

    // ---- cross-wave reduce + normalize (512 outputs, 1 per thread) ----
    {
        int ci = tid & 15, q = (tid >> 4) & 15, br = tid >> 8;
        float v = 0.f, lq = 0.f;
#pragma unroll
        for (int ww = 0; ww < 8; ++ww) {
            v  += ys[(((ww * 2 + br) * 16) + q) * 16 + ci];
            lq += ls[ww * 16 + q];
        }
        y2[q * 33 + br * 16 + ci] = v / lq;
    }
    __syncthreads();

    // ---- epilogue: z = BN(w_W . y + b_W) + residual, both branches ----
    const int q  = tid & 15;
    const int cb = tid >> 4;             // 0..31
#pragma unroll
    for (int i = 0; i < 4; ++i) {
        const int ch2 = cb * 4 + i;      // 0..127
        const int br  = ch2 >> 6;
        const int ch  = ch2 & 63;
        float wy = ldin(b_W, ch, bf);
#pragma unroll
        for (int ci = 0; ci < kCi; ++ci)
            wy = fmaf(ldin(w_W, (size_t)ch * kCi + ci, bf), y2[q * 33 + br * kCi + ci], wy);
        float inv = rsqrtf(ldin(var, ch, bf) + EPS_BN);
        float z = (wy - ldin(mean, ch, bf)) * (ldin(gamma, ch, bf) * inv) + ldin(beta, ch, bf);
        const void* res = br ? bfimg : x;
        z += ldin(res, ((size_t)b * kC + ch) * kN + q0 + q, bf);
        stout(out, ((size_t)b * 2 * kC + ch2) * kN + q0 + q, z, bf);
    }
}

// ---------------------------------------------------------------------------
extern "C" void kernel_launch(void* const* d_in, const int* in_sizes, int n_in,
                              void* d_out, int out_size, void* d_ws, size_t ws_size,
                              hipStream_t stream)
{
    const void* bfimg   = d_in[0];
    const void* x       = d_in[1];
    const void* w_theta = d_in[2];
    const void* b_theta = d_in[3];
    const void* w_phi   = d_in[4];
    const void* b_phi   = d_in[5];
    const void* w_g     = d_in[6];
    const void* b_g     = d_in[7];
    const void* w_gbf   = d_in[8];
    const void* b_gbf   = d_in[9];
    const void* w_W     = d_in[10];
    const void* b_W     = d_in[11];
    const void* gamma   = d_in[12];
    const void* beta    = d_in[13];
    const void* mean    = d_in[14];
    const void* var     = d_in[15];

    char* base = (char*)d_ws;
    char* th_p = base + 256;                               // 2*6400*32 = 409600
    char* ph_p = th_p + (size_t)kB * kN * THB;             // 2*6400*48 = 614400
    char* gx_p = ph_p + (size_t)kB * kN * PHB;             // 2*200*1024 = 409600
    char* gb_p = gx_p + (size_t)kB * (kN / 32) * SGB;      // 409600

    proj_kernel<<<800, 256, 0, stream>>>(
        bfimg, x, w_theta, b_theta, w_phi, b_phi, w_g, b_g, w_gbf, b_gbf,
        th_p, ph_p, gx_p, gb_p);

    attn_kernel<<<kB * (kN / QT), 512, 0, stream>>>(
        th_p, ph_p, gx_p, gb_p,
        bfimg, x, w_W, b_W, gamma, beta, mean, var, d_out);
}

// Round 15
// 131.456 us; speedup vs baseline: 1.0300x; 1.0300x over previous
//
#include <hip/hip_runtime.h>
#include <hip/hip_bf16.h>

typedef __hip_bfloat16 bf16;
typedef __attribute__((ext_vector_type(4))) float f32x4;
typedef __attribute__((ext_vector_type(8))) short bf16x8;

constexpr int kB  = 2;
constexpr int kC  = 64;
constexpr int kCi = 16;
constexpr int kN  = 6400;   // 80*80
constexpr int QT  = 32;     // queries per block (R14: 16->32, halves staging traffic)
constexpr int KT  = 256;    // keys per chunk (8 waves x 32 keys, full-K MFMAs)
constexpr int NCH = kN / KT; // 25

// proj scratch layouts (all bf16):
//   theta: [b][n][ci]                       rows 32 B
//   phi:   [b][n][ci + 8B pad]              rows 48 B (pad unread)
//   gx/gb: 32-key supergroups, 1024 B: row ci (64 B) holds 4 content slots;
//          content slot g stored at PHYSICAL slot (g + (ci>>1)) & 3
constexpr int THB = 32;
constexpr int PHB = 48;
constexpr int SGB = 1024;                  // bytes per 32-key supergroup
constexpr int PH_CH = KT * PHB;            // 12288  (chunk stride, phi)
constexpr int G_CH  = (KT / 32) * SGB;     // 8192   (chunk stride, g)
// per-wave slice: ph 1536 | gx 1024 | gb 1024 = 3584 B
constexpr int WSL  = 3584;
constexpr int W_PH = 1536;
constexpr int W_GX = 1024;
constexpr int BUF_BYTES = 8 * WSL;         // 28672
// LDS: 2*28672 + 1024 theta = 58368 -> 2 blocks/CU

#define EPS_BN 1e-5f

__device__ __forceinline__ float b2f(bf16 v) { return __bfloat162float(v); }
__device__ __forceinline__ unsigned short f2bf(float f) {
    bf16 h = __float2bfloat16(f);
    return *reinterpret_cast<unsigned short*>(&h);
}
__device__ __forceinline__ float ldin(const void* p, size_t i, int bf) {
    return bf ? __bfloat162float(((const bf16*)p)[i]) : ((const float*)p)[i];
}
__device__ __forceinline__ void stout(void* p, size_t i, float v, int bf) {
    if (bf) ((bf16*)p)[i] = __float2bfloat16(v);
    else    ((float*)p)[i] = v;
}
__device__ __forceinline__ void g2lds16(const void* gsrc, void* ldst) {
    __builtin_amdgcn_global_load_lds(
        (const __attribute__((address_space(1))) void*)gsrc,
        (__attribute__((address_space(3))) void*)ldst,
        16, 0, 0);
}
__device__ __forceinline__ unsigned pack2(unsigned short a, unsigned short b) {
    return (unsigned)a | ((unsigned)b << 16);
}
// count "wild" bf16 exponents (e<64 || e>191) in 8 halfwords of a uint4
__device__ __forceinline__ int wild8(uint4 v) {
    int wc = 0;
    unsigned u[4] = {v.x, v.y, v.z, v.w};
#pragma unroll
    for (int i = 0; i < 4; ++i) {
        int e0 = (u[i] >> 7)  & 0xFF;
        int e1 = (u[i] >> 23) & 0xFF;
        wc += (e0 < 64 || e0 > 191);
        wc += (e1 < 64 || e1 > 191);
    }
    return wc;
}

// ---------------------------------------------------------------------------
// Kernel 1: projections -> bf16 in MFMA-ready layouts (UNCHANGED from R13).
// ---------------------------------------------------------------------------
__global__ __launch_bounds__(256)
void proj_kernel(const void* __restrict__ bfimg, const void* __restrict__ x,
                 const void* __restrict__ w_theta, const void* __restrict__ b_theta,
                 const void* __restrict__ w_phi,   const void* __restrict__ b_phi,
                 const void* __restrict__ w_g,     const void* __restrict__ b_g,
                 const void* __restrict__ w_gbf,   const void* __restrict__ b_gbf,
                 char* __restrict__ th_p, char* __restrict__ ph_p,
                 char* __restrict__ gx_p, char* __restrict__ gb_p)
{
    __shared__ float w_s[kCi][kC];                 // 4 KB
    __shared__ float b_s[kCi];
    __shared__ __align__(16) char out_s[64 * PHB]; // 3072 B (>= 2048 g-bytes)
    __shared__ int dred[4];

    const int tid = threadIdx.x;
    const int wv  = tid >> 6;
    const int l   = tid & 63;

    // ---- dtype self-detect ----
    int wc = wild8(*(const uint4*)((const char*)bfimg + tid * 16));
#pragma unroll
    for (int off = 32; off > 0; off >>= 1) wc += __shfl_down(wc, off);
    if (l == 0) dred[wv] = wc;
    __syncthreads();
    const int bf = ((dred[0] + dred[1] + dred[2] + dred[3]) * 8 < 2048) ? 1 : 0;

    const int bid = blockIdx.x;        // [0, 800)
    const int sec = bid / 200;         // 0..3
    const int r   = bid % 200;
    const int b   = r / 100;
    const int t64 = r % 100;
    const int n0  = t64 * 64;

    const void *src, *w, *bias;
    if (sec == 0)      { src = bfimg; w = w_theta; bias = b_theta; }
    else if (sec == 1) { src = bfimg; w = w_phi;   bias = b_phi;   }
    else if (sec == 2) { src = x;     w = w_g;     bias = b_g;     }
    else               { src = bfimg; w = w_gbf;   bias = b_gbf;   }

    for (int i = tid; i < kCi * kC; i += 256)
        w_s[i >> 6][i & 63] = ldin(w, i, bf);
    if (tid < kCi) b_s[tid] = ldin(bias, tid, bf);
    __syncthreads();

    const int px = tid & 63;
    const int cg = tid >> 6;           // ci quad
    const int n  = n0 + px;

    float a0 = b_s[cg * 4 + 0], a1 = b_s[cg * 4 + 1];
    float a2 = b_s[cg * 4 + 2], a3 = b_s[cg * 4 + 3];
    const size_t ibase = (size_t)b * kC * kN + n;
#pragma unroll 8
    for (int ch = 0; ch < kC; ++ch) {
        float v = ldin(src, ibase + (size_t)ch * kN, bf);
        a0 = fmaf(w_s[cg * 4 + 0][ch], v, a0);
        a1 = fmaf(w_s[cg * 4 + 1][ch], v, a1);
        a2 = fmaf(w_s[cg * 4 + 2][ch], v, a2);
        a3 = fmaf(w_s[cg * 4 + 3][ch], v, a3);
    }

    if (sec < 2) {
        const int RB = sec ? PHB : THB;
        uint2 v; v.x = pack2(f2bf(a0), f2bf(a1)); v.y = pack2(f2bf(a2), f2bf(a3));
        *(uint2*)(out_s + px * RB + cg * 8) = v;
        __syncthreads();
        const int bytes = 64 * RB;
        char* dst = (sec ? ph_p : th_p) + ((size_t)b * kN + n0) * RB;
        for (int i = tid * 16; i < bytes; i += 256 * 16)
            *(uint4*)(dst + i) = *(const uint4*)(out_s + i);
    } else {
        // swizzled supergroup layout: this thread's 4 keys are r=4*gg+k
        const int k  = px & 3;
        const int Gl = px >> 2;            // 0..15 local 4-key group
        const int sg = Gl >> 3;            // 0/1 local supergroup
        const int gg = Gl & 7;
        const int inner = (gg >> 2) * 8 + k * 2;
        const int s_c   = gg & 3;          // content slot
#pragma unroll
        for (int j = 0; j < 4; ++j) {
            const int ci = cg * 4 + j;
            const int s_p = (s_c + (ci >> 1)) & 3;    // physical slot (swizzle)
            const float av = (j == 0) ? a0 : (j == 1) ? a1 : (j == 2) ? a2 : a3;
            *(unsigned short*)(out_s + sg * SGB + ci * 64 + s_p * 16 + inner) = f2bf(av);
        }
        __syncthreads();
        const int bytes = 2 * SGB;         // 2048
        char* dst = (sec == 2 ? gx_p : gb_p)
                  + (size_t)b * (kN / 32) * SGB + (size_t)(n0 >> 5) * SGB;
        for (int i = tid * 16; i < bytes; i += 256 * 16)
            *(uint4*)(dst + i) = *(const uint4*)(out_s + i);
    }
}

// ---------------------------------------------------------------------------
// Kernel 2: MFMA attention, barrier-free, 8 waves x 32 keys, KT=256, QT=32.
// 32 queries per block (bq0: q 0-15, bq1: q 16-31) -> 400 blocks,
// staged L2 traffic HALVES (573 -> 287 MB/dispatch) at identical wave-private
// slice geometry. Per chunk per wave: 4 QK MFMA + 16 exp + 4 PV MFMA.
// ---------------------------------------------------------------------------
__global__ __launch_bounds__(512, 4)
void attn_kernel(const char* __restrict__ th_p, const char* __restrict__ ph_p,
                 const char* __restrict__ gx_p, const char* __restrict__ gb_p,
                 const void* __restrict__ bfimg, const void* __restrict__ x,
                 const void* __restrict__ w_W,  const void* __restrict__ b_W,
                 const void* __restrict__ gamma, const void* __restrict__ beta,
                 const void* __restrict__ mean,  const void* __restrict__ var,
                 void* __restrict__ out)
{
    __shared__ __align__(16) char smem[2 * BUF_BYTES + 1024];  // 58368 B

    const int tid = threadIdx.x;
    const int w   = tid >> 6;          // 0..7
    const int l   = tid & 63;
    const int g   = l >> 4;            // 0..3
    const int h   = l & 15;
    const int b   = blockIdx.x / (kN / QT);
    const int q0  = (blockIdx.x % (kN / QT)) * QT;

    // ---- dtype self-detect sample (reduced after main loop) ----
    int wc = wild8(*(const uint4*)((const char*)bfimg + tid * 16));

    // ---- wave-private DMA plan: instr R, slice byte ofs = R*1024 + l*16
    //      regions: ph [0,1536) | gx [1536,2560) | gb [2560,3584)
    const char* srcp[4]; int strv[4]; int dofs[4];
#pragma unroll
    for (int R = 0; R < 4; ++R) {
        int ofs = R * 1024 + l * 16;
        if (ofs < W_PH) {
            srcp[R] = ph_p + (size_t)b * kN * PHB + (size_t)w * W_PH + ofs;
            strv[R] = PH_CH;
        } else if (ofs < W_PH + W_GX) {
            srcp[R] = gx_p + (size_t)b * (kN / 32) * SGB + (size_t)w * SGB + (ofs - W_PH);
            strv[R] = G_CH;
        } else {
            srcp[R] = gb_p + (size_t)b * (kN / 32) * SGB + (size_t)w * SGB + (ofs - W_PH - W_GX);
            strv[R] = G_CH;
        }
        dofs[R] = w * WSL + ofs;
    }
#define STAGE(it, sel)                                                      \
    {                                                                       \
        g2lds16(srcp[0] + (size_t)(it) * strv[0], smem + (sel) * BUF_BYTES + dofs[0]); \
        g2lds16(srcp[1] + (size_t)(it) * strv[1], smem + (sel) * BUF_BYTES + dofs[1]); \
        g2lds16(srcp[2] + (size_t)(it) * strv[2], smem + (sel) * BUF_BYTES + dofs[2]); \
        if (l < 32)                                                         \
            g2lds16(srcp[3] + (size_t)(it) * strv[3], smem + (sel) * BUF_BYTES + dofs[3]); \
    }

    // ---- prologue: chunk 0 + theta tile (32 rows = 1024 B, all 512 threads)
    STAGE(0, 0);
    ((unsigned short*)(smem + 2 * BUF_BYTES))[tid] =
        *(const unsigned short*)(th_p + ((size_t)b * kN + q0) * THB + tid * 2);
    __syncthreads();                      // theta visible + stage 0 drained

    bf16x8 bq0, bq1;
#pragma unroll
    for (int j = 0; j < 8; ++j) { bq0[j] = 0; bq1[j] = 0; }
    if (g < 2) {
        bq0 = *(const bf16x8*)(smem + 2 * BUF_BYTES + h * THB + g * 16);
        bq1 = *(const bf16x8*)(smem + 2 * BUF_BYTES + (16 + h) * THB + g * 16);
    }

    // swizzled PV slot offset for this lane (constant across chunks)
    const int pv_off = h * 64 + (((g + (h >> 1)) & 3) << 4);

    const f32x4 z4 = {0.f, 0.f, 0.f, 0.f};
    f32x4 accx0 = z4, accb0 = z4, accx1 = z4, accb1 = z4;
    float lsum0 = 0.f, lsum1 = 0.f;

    auto compute = [&](int it) {
        const char* wbuf = smem + (it & 1) * BUF_BYTES + w * WSL;

        // --- QK^T: A = phi rows (wave's two 16-key tiles) x both q-tiles ---
        bf16x8 a0, a1;
#pragma unroll
        for (int j = 0; j < 8; ++j) { a0[j] = 0; a1[j] = 0; }
        if (g < 2) {
            a0 = *(const bf16x8*)(wbuf + h * PHB + g * 16);
            a1 = *(const bf16x8*)(wbuf + (16 + h) * PHB + g * 16);
        }
        f32x4 s00 = __builtin_amdgcn_mfma_f32_16x16x32_bf16(a0, bq0, z4, 0, 0, 0);
        f32x4 s01 = __builtin_amdgcn_mfma_f32_16x16x32_bf16(a1, bq0, z4, 0, 0, 0);
        f32x4 s10 = __builtin_amdgcn_mfma_f32_16x16x32_bf16(a0, bq1, z4, 0, 0, 0);
        f32x4 s11 = __builtin_amdgcn_mfma_f32_16x16x32_bf16(a1, bq1, z4, 0, 0, 0);

        // --- softmax numerators (exact, no max-sub), q-tile 0 ---
        float p0 = __expf(s00[0]), p1 = __expf(s00[1]), p2 = __expf(s00[2]), p3 = __expf(s00[3]);
        float p4 = __expf(s01[0]), p5 = __expf(s01[1]), p6 = __expf(s01[2]), p7 = __expf(s01[3]);
        lsum0 += (p0 + p1) + (p2 + p3) + (p4 + p5) + (p6 + p7);
        union { unsigned short u[8]; bf16x8 v; } pa0;
        pa0.u[0] = f2bf(p0); pa0.u[1] = f2bf(p1); pa0.u[2] = f2bf(p2); pa0.u[3] = f2bf(p3);
        pa0.u[4] = f2bf(p4); pa0.u[5] = f2bf(p5); pa0.u[6] = f2bf(p6); pa0.u[7] = f2bf(p7);

        // --- q-tile 1 ---
        float r0 = __expf(s10[0]), r1 = __expf(s10[1]), r2 = __expf(s10[2]), r3 = __expf(s10[3]);
        float r4 = __expf(s11[0]), r5 = __expf(s11[1]), r6 = __expf(s11[2]), r7 = __expf(s11[3]);
        lsum1 += (r0 + r1) + (r2 + r3) + (r4 + r5) + (r6 + r7);
        union { unsigned short u[8]; bf16x8 v; } pa1;
        pa1.u[0] = f2bf(r0); pa1.u[1] = f2bf(r1); pa1.u[2] = f2bf(r2); pa1.u[3] = f2bf(r3);
        pa1.u[4] = f2bf(r4); pa1.u[5] = f2bf(r5); pa1.u[6] = f2bf(r6); pa1.u[7] = f2bf(r7);

        // --- PV: one b128 per branch, swizzled slot (2-way banks) ---
        bf16x8 bx = *(const bf16x8*)(wbuf + W_PH + pv_off);
        bf16x8 bb = *(const bf16x8*)(wbuf + W_PH + W_GX + pv_off);

        accx0 = __builtin_amdgcn_mfma_f32_16x16x32_bf16(pa0.v, bx, accx0, 0, 0, 0);
        accb0 = __builtin_amdgcn_mfma_f32_16x16x32_bf16(pa0.v, bb, accb0, 0, 0, 0);
        accx1 = __builtin_amdgcn_mfma_f32_16x16x32_bf16(pa1.v, bx, accx1, 0, 0, 0);
        accb1 = __builtin_amdgcn_mfma_f32_16x16x32_bf16(pa1.v, bb, accb1, 0, 0, 0);
    };

    // ---- barrier-free main loop: counted vmcnt, wave-private slices ----
    for (int it = 0; it < NCH - 1; ++it) {
        STAGE(it + 1, (it + 1) & 1);
        asm volatile("s_waitcnt vmcnt(4)" ::: "memory");   // stage(it) done
        __builtin_amdgcn_sched_barrier(0);
        compute(it);
    }
    asm volatile("s_waitcnt vmcnt(0)" ::: "memory");       // last chunk done
    __builtin_amdgcn_sched_barrier(0);
    compute(NCH - 1);
#undef STAGE

    // ---- reduce l across lane-groups: lanes 0-15 hold q=l / q=16+l totals
    lsum0 += __shfl_down(lsum0, 16);
    lsum0 += __shfl_down(lsum0, 32);
    lsum1 += __shfl_down(lsum1, 16);
    lsum1 += __shfl_down(lsum1, 32);
#pragma unroll
    for (int off = 32; off > 0; off >>= 1) wc += __shfl_down(wc, off);

    // FENCE before LDS reuse: all waves past their last buffer reads.
    __syncthreads();

    // buffers dead; reuse LDS
    float* ys = (float*)smem;            // [8w][2br][32q][16ci] 32768 B
    float* ls = (float*)(smem + 32768);  // [8w][32q]            1024 B
    float* y2 = (float*)(smem + 33792);  // [32q][33]            4224 B
    int*   wd = (int*)(smem + 38016);    // [8w]                 32 B
    if (l < 16) {
        ls[w * 32 + l]      = lsum0;
        ls[w * 32 + 16 + l] = lsum1;
    }
    if (l == 0) wd[w] = wc;
#pragma unroll
    for (int r = 0; r < 4; ++r) {
        int q = g * 4 + r;               // verified D layout: row=(lane>>4)*4+r
        ys[(((w * 2 + 0) * 32) + q) * 16 + h]      = accx0[r];
        ys[(((w * 2 + 1) * 32) + q) * 16 + h]      = accb0[r];
        ys[(((w * 2 + 0) * 32) + 16 + q) * 16 + h] = accx1[r];
        ys[(((w * 2 + 1) * 32) + 16 + q) * 16 + h] = accb1[r];
    }
    __syncthreads();

    const int bf = ((wd[0] + wd[1] + wd[2] + wd[3] +
                     wd[4] + wd[5] + wd[6] + wd[7]) * 8 < 4096) ? 1 : 0;

    // ---- cross-wave reduce + normalize (1024 outputs, 2 per thread) ----
    for (int i = tid; i < 1024; i += 512) {
        int ci = i & 15, q = (i >> 4) & 31, br = i >> 9;
        float v = 0.f, lq = 0.f;
#pragma unroll
        for (int ww = 0; ww < 8; ++ww) {
            v  += ys[(((ww * 2 + br) * 32) + q) * 16 + ci];
            lq += ls[ww * 32 + q];
        }
        y2[q * 33 + br * 16 + ci] = v / lq;
    }
    __syncthreads();

    // ---- epilogue: z = BN(w_W . y + b_W) + residual, both branches ----
    const int q  = tid & 31;
    const int cb = tid >> 5;             // 0..15
#pragma unroll
    for (int i = 0; i < 8; ++i) {
        const int ch2 = cb * 8 + i;      // 0..127
        const int br  = ch2 >> 6;
        const int ch  = ch2 & 63;
        float wy = ldin(b_W, ch, bf);
#pragma unroll
        for (int ci = 0; ci < kCi; ++ci)
            wy = fmaf(ldin(w_W, (size_t)ch * kCi + ci, bf), y2[q * 33 + br * kCi + ci], wy);
        float inv = rsqrtf(ldin(var, ch, bf) + EPS_BN);
        float z = (wy - ldin(mean, ch, bf)) * (ldin(gamma, ch, bf) * inv) + ldin(beta, ch, bf);
        const void* res = br ? bfimg : x;
        z += ldin(res, ((size_t)b * kC + ch) * kN + q0 + q, bf);
        stout(out, ((size_t)b * 2 * kC + ch2) * kN + q0 + q, z, bf);
    }
}

// ---------------------------------------------------------------------------
extern "C" void kernel_launch(void* const* d_in, const int* in_sizes, int n_in,
                              void* d_out, int out_size, void* d_ws, size_t ws_size,
                              hipStream_t stream)
{
    const void* bfimg   = d_in[0];
    const void* x       = d_in[1];
    const void* w_theta = d_in[2];
    const void* b_theta = d_in[3];
    const void* w_phi   = d_in[4];
    const void* b_phi   = d_in[5];
    const void* w_g     = d_in[6];
    const void* b_g     = d_in[7];
    const void* w_gbf   = d_in[8];
    const void* b_gbf   = d_in[9];
    const void* w_W     = d_in[10];
    const void* b_W     = d_in[11];
    const void* gamma   = d_in[12];
    const void* beta    = d_in[13];
    const void* mean    = d_in[14];
    const void* var     = d_in[15];

    char* base = (char*)d_ws;
    char* th_p = base + 256;                               // 2*6400*32 = 409600
    char* ph_p = th_p + (size_t)kB * kN * THB;             // 2*6400*48 = 614400
    char* gx_p = ph_p + (size_t)kB * kN * PHB;             // 2*200*1024 = 409600
    char* gb_p = gx_p + (size_t)kB * (kN / 32) * SGB;      // 409600

    proj_kernel<<<800, 256, 0, stream>>>(
        bfimg, x, w_theta, b_theta, w_phi, b_phi, w_g, b_g, w_gbf, b_gbf,
        th_p, ph_p, gx_p, gb_p);

    attn_kernel<<<kB * (kN / QT), 512, 0, stream>>>(
        th_p, ph_p, gx_p, gb_p,
        bfimg, x, w_W, b_W, gamma, beta, mean, var, d_out);
}

// Round 17
// 127.160 us; speedup vs baseline: 1.0647x; 1.0338x over previous
//
#include <hip/hip_runtime.h>
#include <hip/hip_bf16.h>

typedef __hip_bfloat16 bf16;
typedef __attribute__((ext_vector_type(4))) float f32x4;
typedef __attribute__((ext_vector_type(8))) short bf16x8;

constexpr int kB  = 2;
constexpr int kC  = 64;
constexpr int kCi = 16;
constexpr int kN  = 6400;   // 80*80
constexpr int QT  = 32;     // queries per block
constexpr int KT  = 256;    // keys per chunk (8 waves x 32 keys, full-K MFMAs)
constexpr int NCH = kN / KT; // 25

// proj scratch layouts (all bf16):
//   theta: [b][n][ci]                       rows 32 B
//   phi:   [b][n][ci + 8B pad]              rows 48 B (pad unread)
//   gx/gb: 32-key supergroups, 1024 B: row ci (64 B) holds 4 content slots;
//          content slot g stored at PHYSICAL slot (g + (ci>>1)) & 3
constexpr int THB = 32;
constexpr int PHB = 48;
constexpr int SGB = 1024;                  // bytes per 32-key supergroup
constexpr int PH_CH = KT * PHB;            // 12288  (chunk stride, phi)
constexpr int G_CH  = (KT / 32) * SGB;     // 8192   (chunk stride, g)
// per-wave slice: ph 1536 | gx 1024 | gb 1024 = 3584 B
constexpr int WSL  = 3584;
constexpr int W_PH = 1536;
constexpr int W_GX = 1024;
constexpr int BUF_BYTES = 8 * WSL;         // 28672
// LDS: 2*28672 + 1024 theta = 58368 -> 2 blocks/CU

#define EPS_BN 1e-5f

__device__ __forceinline__ float b2f(bf16 v) { return __bfloat162float(v); }
__device__ __forceinline__ unsigned short f2bf(float f) {
    bf16 h = __float2bfloat16(f);
    return *reinterpret_cast<unsigned short*>(&h);
}
__device__ __forceinline__ float ldin(const void* p, size_t i, int bf) {
    return bf ? __bfloat162float(((const bf16*)p)[i]) : ((const float*)p)[i];
}
__device__ __forceinline__ void stout(void* p, size_t i, float v, int bf) {
    if (bf) ((bf16*)p)[i] = __float2bfloat16(v);
    else    ((float*)p)[i] = v;
}
__device__ __forceinline__ void g2lds16(const void* gsrc, void* ldst) {
    __builtin_amdgcn_global_load_lds(
        (const __attribute__((address_space(1))) void*)gsrc,
        (__attribute__((address_space(3))) void*)ldst,
        16, 0, 0);
}
__device__ __forceinline__ unsigned pack2(unsigned short a, unsigned short b) {
    return (unsigned)a | ((unsigned)b << 16);
}
// count "wild" bf16 exponents (e<64 || e>191) in 8 halfwords of a uint4
__device__ __forceinline__ int wild8(uint4 v) {
    int wc = 0;
    unsigned u[4] = {v.x, v.y, v.z, v.w};
#pragma unroll
    for (int i = 0; i < 4; ++i) {
        int e0 = (u[i] >> 7)  & 0xFF;
        int e1 = (u[i] >> 23) & 0xFF;
        wc += (e0 < 64 || e0 > 191);
        wc += (e1 < 64 || e1 > 191);
    }
    return wc;
}

// ---------------------------------------------------------------------------
// Kernel 1: projections -> bf16 in MFMA-ready layouts (REVERTED to the
// R13/R15-proven version; R16's 4px-quad retile had an OOB cg mapping).
// Grid = 800 blocks; block = (sec, b, 64-pixel tile).
// ---------------------------------------------------------------------------
__global__ __launch_bounds__(256)
void proj_kernel(const void* __restrict__ bfimg, const void* __restrict__ x,
                 const void* __restrict__ w_theta, const void* __restrict__ b_theta,
                 const void* __restrict__ w_phi,   const void* __restrict__ b_phi,
                 const void* __restrict__ w_g,     const void* __restrict__ b_g,
                 const void* __restrict__ w_gbf,   const void* __restrict__ b_gbf,
                 char* __restrict__ th_p, char* __restrict__ ph_p,
                 char* __restrict__ gx_p, char* __restrict__ gb_p)
{
    __shared__ float w_s[kCi][kC];                 // 4 KB
    __shared__ float b_s[kCi];
    __shared__ __align__(16) char out_s[64 * PHB]; // 3072 B (>= 2048 g-bytes)
    __shared__ int dred[4];

    const int tid = threadIdx.x;
    const int wv  = tid >> 6;
    const int l   = tid & 63;

    // ---- dtype self-detect ----
    int wc = wild8(*(const uint4*)((const char*)bfimg + tid * 16));
#pragma unroll
    for (int off = 32; off > 0; off >>= 1) wc += __shfl_down(wc, off);
    if (l == 0) dred[wv] = wc;
    __syncthreads();
    const int bf = ((dred[0] + dred[1] + dred[2] + dred[3]) * 8 < 2048) ? 1 : 0;

    const int bid = blockIdx.x;        // [0, 800)
    const int sec = bid / 200;         // 0..3
    const int r   = bid % 200;
    const int b   = r / 100;
    const int t64 = r % 100;
    const int n0  = t64 * 64;

    const void *src, *w, *bias;
    if (sec == 0)      { src = bfimg; w = w_theta; bias = b_theta; }
    else if (sec == 1) { src = bfimg; w = w_phi;   bias = b_phi;   }
    else if (sec == 2) { src = x;     w = w_g;     bias = b_g;     }
    else               { src = bfimg; w = w_gbf;   bias = b_gbf;   }

    for (int i = tid; i < kCi * kC; i += 256)
        w_s[i >> 6][i & 63] = ldin(w, i, bf);
    if (tid < kCi) b_s[tid] = ldin(bias, tid, bf);
    __syncthreads();

    const int px = tid & 63;
    const int cg = tid >> 6;           // ci quad (0..3)
    const int n  = n0 + px;

    float a0 = b_s[cg * 4 + 0], a1 = b_s[cg * 4 + 1];
    float a2 = b_s[cg * 4 + 2], a3 = b_s[cg * 4 + 3];
    const size_t ibase = (size_t)b * kC * kN + n;
#pragma unroll 8
    for (int ch = 0; ch < kC; ++ch) {
        float v = ldin(src, ibase + (size_t)ch * kN, bf);
        a0 = fmaf(w_s[cg * 4 + 0][ch], v, a0);
        a1 = fmaf(w_s[cg * 4 + 1][ch], v, a1);
        a2 = fmaf(w_s[cg * 4 + 2][ch], v, a2);
        a3 = fmaf(w_s[cg * 4 + 3][ch], v, a3);
    }

    if (sec < 2) {
        const int RB = sec ? PHB : THB;
        uint2 v; v.x = pack2(f2bf(a0), f2bf(a1)); v.y = pack2(f2bf(a2), f2bf(a3));
        *(uint2*)(out_s + px * RB + cg * 8) = v;
        __syncthreads();
        const int bytes = 64 * RB;
        char* dst = (sec ? ph_p : th_p) + ((size_t)b * kN + n0) * RB;
        for (int i = tid * 16; i < bytes; i += 256 * 16)
            *(uint4*)(dst + i) = *(const uint4*)(out_s + i);
    } else {
        // swizzled supergroup layout: this thread's 4 keys are r=4*gg+k
        const int k  = px & 3;
        const int Gl = px >> 2;            // 0..15 local 4-key group
        const int sg = Gl >> 3;            // 0/1 local supergroup
        const int gg = Gl & 7;
        const int inner = (gg >> 2) * 8 + k * 2;
        const int s_c   = gg & 3;          // content slot
#pragma unroll
        for (int j = 0; j < 4; ++j) {
            const int ci = cg * 4 + j;
            const int s_p = (s_c + (ci >> 1)) & 3;    // physical slot (swizzle)
            const float av = (j == 0) ? a0 : (j == 1) ? a1 : (j == 2) ? a2 : a3;
            *(unsigned short*)(out_s + sg * SGB + ci * 64 + s_p * 16 + inner) = f2bf(av);
        }
        __syncthreads();
        const int bytes = 2 * SGB;         // 2048
        char* dst = (sec == 2 ? gx_p : gb_p)
                  + (size_t)b * (kN / 32) * SGB + (size_t)(n0 >> 5) * SGB;
        for (int i = tid * 16; i < bytes; i += 256 * 16)
            *(uint4*)(dst + i) = *(const uint4*)(out_s + i);
    }
}

// ---------------------------------------------------------------------------
// Kernel 2: MFMA attention, barrier-free, 8 waves x 32 keys, KT=256, QT=32.
// R17: identical to R15 + s_setprio(1/0) around the compute body (T5) --
// drifting waves sit at different phases, so the scheduler can favor
// compute-phase waves over load-issuing ones.
// ---------------------------------------------------------------------------
__global__ __launch_bounds__(512, 4)
void attn_kernel(const char* __restrict__ th_p, const char* __restrict__ ph_p,
                 const char* __restrict__ gx_p, const char* __restrict__ gb_p,
                 const void* __restrict__ bfimg, const void* __restrict__ x,
                 const void* __restrict__ w_W,  const void* __restrict__ b_W,
                 const void* __restrict__ gamma, const void* __restrict__ beta,
                 const void* __restrict__ mean,  const void* __restrict__ var,
                 void* __restrict__ out)
{
    __shared__ __align__(16) char smem[2 * BUF_BYTES + 1024];  // 58368 B

    const int tid = threadIdx.x;
    const int w   = tid >> 6;          // 0..7
    const int l   = tid & 63;
    const int g   = l >> 4;            // 0..3
    const int h   = l & 15;
    const int b   = blockIdx.x / (kN / QT);
    const int q0  = (blockIdx.x % (kN / QT)) * QT;

    // ---- dtype self-detect sample (reduced after main loop) ----
    int wc = wild8(*(const uint4*)((const char*)bfimg + tid * 16));

    // ---- wave-private DMA plan: instr R, slice byte ofs = R*1024 + l*16
    //      regions: ph [0,1536) | gx [1536,2560) | gb [2560,3584)
    const char* srcp[4]; int strv[4]; int dofs[4];
#pragma unroll
    for (int R = 0; R < 4; ++R) {
        int ofs = R * 1024 + l * 16;
        if (ofs < W_PH) {
            srcp[R] = ph_p + (size_t)b * kN * PHB + (size_t)w * W_PH + ofs;
            strv[R] = PH_CH;
        } else if (ofs < W_PH + W_GX) {
            srcp[R] = gx_p + (size_t)b * (kN / 32) * SGB + (size_t)w * SGB + (ofs - W_PH);
            strv[R] = G_CH;
        } else {
            srcp[R] = gb_p + (size_t)b * (kN / 32) * SGB + (size_t)w * SGB + (ofs - W_PH - W_GX);
            strv[R] = G_CH;
        }
        dofs[R] = w * WSL + ofs;
    }
#define STAGE(it, sel)                                                      \
    {                                                                       \
        g2lds16(srcp[0] + (size_t)(it) * strv[0], smem + (sel) * BUF_BYTES + dofs[0]); \
        g2lds16(srcp[1] + (size_t)(it) * strv[1], smem + (sel) * BUF_BYTES + dofs[1]); \
        g2lds16(srcp[2] + (size_t)(it) * strv[2], smem + (sel) * BUF_BYTES + dofs[2]); \
        if (l < 32)                                                         \
            g2lds16(srcp[3] + (size_t)(it) * strv[3], smem + (sel) * BUF_BYTES + dofs[3]); \
    }

    // ---- prologue: chunk 0 + theta tile (32 rows = 1024 B, all 512 threads)
    STAGE(0, 0);
    ((unsigned short*)(smem + 2 * BUF_BYTES))[tid] =
        *(const unsigned short*)(th_p + ((size_t)b * kN + q0) * THB + tid * 2);
    __syncthreads();                      // theta visible + stage 0 drained

    bf16x8 bq0, bq1;
#pragma unroll
    for (int j = 0; j < 8; ++j) { bq0[j] = 0; bq1[j] = 0; }
    if (g < 2) {
        bq0 = *(const bf16x8*)(smem + 2 * BUF_BYTES + h * THB + g * 16);
        bq1 = *(const bf16x8*)(smem + 2 * BUF_BYTES + (16 + h) * THB + g * 16);
    }

    // swizzled PV slot offset for this lane (constant across chunks)
    const int pv_off = h * 64 + (((g + (h >> 1)) & 3) << 4);

    const f32x4 z4 = {0.f, 0.f, 0.f, 0.f};
    f32x4 accx0 = z4, accb0 = z4, accx1 = z4, accb1 = z4;
    float lsum0 = 0.f, lsum1 = 0.f;

    auto compute = [&](int it) {
        const char* wbuf = smem + (it & 1) * BUF_BYTES + w * WSL;
        __builtin_amdgcn_s_setprio(1);

        // --- QK^T: A = phi rows (wave's two 16-key tiles) x both q-tiles ---
        bf16x8 a0, a1;
#pragma unroll
        for (int j = 0; j < 8; ++j) { a0[j] = 0; a1[j] = 0; }
        if (g < 2) {
            a0 = *(const bf16x8*)(wbuf + h * PHB + g * 16);
            a1 = *(const bf16x8*)(wbuf + (16 + h) * PHB + g * 16);
        }
        f32x4 s00 = __builtin_amdgcn_mfma_f32_16x16x32_bf16(a0, bq0, z4, 0, 0, 0);
        f32x4 s01 = __builtin_amdgcn_mfma_f32_16x16x32_bf16(a1, bq0, z4, 0, 0, 0);
        f32x4 s10 = __builtin_amdgcn_mfma_f32_16x16x32_bf16(a0, bq1, z4, 0, 0, 0);
        f32x4 s11 = __builtin_amdgcn_mfma_f32_16x16x32_bf16(a1, bq1, z4, 0, 0, 0);

        // --- softmax numerators (exact, no max-sub), q-tile 0 ---
        float p0 = __expf(s00[0]), p1 = __expf(s00[1]), p2 = __expf(s00[2]), p3 = __expf(s00[3]);
        float p4 = __expf(s01[0]), p5 = __expf(s01[1]), p6 = __expf(s01[2]), p7 = __expf(s01[3]);
        lsum0 += (p0 + p1) + (p2 + p3) + (p4 + p5) + (p6 + p7);
        union { unsigned short u[8]; bf16x8 v; } pa0;
        pa0.u[0] = f2bf(p0); pa0.u[1] = f2bf(p1); pa0.u[2] = f2bf(p2); pa0.u[3] = f2bf(p3);
        pa0.u[4] = f2bf(p4); pa0.u[5] = f2bf(p5); pa0.u[6] = f2bf(p6); pa0.u[7] = f2bf(p7);

        // --- q-tile 1 ---
        float r0 = __expf(s10[0]), r1 = __expf(s10[1]), r2 = __expf(s10[2]), r3 = __expf(s10[3]);
        float r4 = __expf(s11[0]), r5 = __expf(s11[1]), r6 = __expf(s11[2]), r7 = __expf(s11[3]);
        lsum1 += (r0 + r1) + (r2 + r3) + (r4 + r5) + (r6 + r7);
        union { unsigned short u[8]; bf16x8 v; } pa1;
        pa1.u[0] = f2bf(r0); pa1.u[1] = f2bf(r1); pa1.u[2] = f2bf(r2); pa1.u[3] = f2bf(r3);
        pa1.u[4] = f2bf(r4); pa1.u[5] = f2bf(r5); pa1.u[6] = f2bf(r6); pa1.u[7] = f2bf(r7);

        // --- PV: one b128 per branch, swizzled slot (2-way banks) ---
        bf16x8 bx = *(const bf16x8*)(wbuf + W_PH + pv_off);
        bf16x8 bb = *(const bf16x8*)(wbuf + W_PH + W_GX + pv_off);

        accx0 = __builtin_amdgcn_mfma_f32_16x16x32_bf16(pa0.v, bx, accx0, 0, 0, 0);
        accb0 = __builtin_amdgcn_mfma_f32_16x16x32_bf16(pa0.v, bb, accb0, 0, 0, 0);
        accx1 = __builtin_amdgcn_mfma_f32_16x16x32_bf16(pa1.v, bx, accx1, 0, 0, 0);
        accb1 = __builtin_amdgcn_mfma_f32_16x16x32_bf16(pa1.v, bb, accb1, 0, 0, 0);
        __builtin_amdgcn_s_setprio(0);
    };

    // ---- barrier-free main loop: counted vmcnt, wave-private slices ----
    for (int it = 0; it < NCH - 1; ++it) {
        STAGE(it + 1, (it + 1) & 1);
        asm volatile("s_waitcnt vmcnt(4)" ::: "memory");   // stage(it) done
        __builtin_amdgcn_sched_barrier(0);
        compute(it);
    }
    asm volatile("s_waitcnt vmcnt(0)" ::: "memory");       // last chunk done
    __builtin_amdgcn_sched_barrier(0);
    compute(NCH - 1);
#undef STAGE

    // ---- reduce l across lane-groups: lanes 0-15 hold q=l / q=16+l totals
    lsum0 += __shfl_down(lsum0, 16);
    lsum0 += __shfl_down(lsum0, 32);
    lsum1 += __shfl_down(lsum1, 16);
    lsum1 += __shfl_down(lsum1, 32);
#pragma unroll
    for (int off = 32; off > 0; off >>= 1) wc += __shfl_down(wc, off);

    // FENCE before LDS reuse: all waves past their last buffer reads.
    __syncthreads();

    // buffers dead; reuse LDS
    float* ys = (float*)smem;            // [8w][2br][32q][16ci] 32768 B
    float* ls = (float*)(smem + 32768);  // [8w][32q]            1024 B
    float* y2 = (float*)(smem + 33792);  // [32q][33]            4224 B
    int*   wd = (int*)(smem + 38016);    // [8w]                 32 B
    if (l < 16) {
        ls[w * 32 + l]      = lsum0;
        ls[w * 32 + 16 + l] = lsum1;
    }
    if (l == 0) wd[w] = wc;
#pragma unroll
    for (int r = 0; r < 4; ++r) {
        int q = g * 4 + r;               // verified D layout: row=(lane>>4)*4+r
        ys[(((w * 2 + 0) * 32) + q) * 16 + h]      = accx0[r];
        ys[(((w * 2 + 1) * 32) + q) * 16 + h]      = accb0[r];
        ys[(((w * 2 + 0) * 32) + 16 + q) * 16 + h] = accx1[r];
        ys[(((w * 2 + 1) * 32) + 16 + q) * 16 + h] = accb1[r];
    }
    __syncthreads();

    const int bf = ((wd[0] + wd[1] + wd[2] + wd[3] +
                     wd[4] + wd[5] + wd[6] + wd[7]) * 8 < 4096) ? 1 : 0;

    // ---- cross-wave reduce + normalize (1024 outputs, 2 per thread) ----
    for (int i = tid; i < 1024; i += 512) {
        int ci = i & 15, q = (i >> 4) & 31, br = i >> 9;
        float v = 0.f, lq = 0.f;
#pragma unroll
        for (int ww = 0; ww < 8; ++ww) {
            v  += ys[(((ww * 2 + br) * 32) + q) * 16 + ci];
            lq += ls[ww * 32 + q];
        }
        y2[q * 33 + br * 16 + ci] = v / lq;
    }
    __syncthreads();

    // ---- epilogue: z = BN(w_W . y + b_W) + residual, both branches ----
    const int q  = tid & 31;
    const int cb = tid >> 5;             // 0..15
#pragma unroll
    for (int i = 0; i < 8; ++i) {
        const int ch2 = cb * 8 + i;      // 0..127
        const int br  = ch2 >> 6;
        const int ch  = ch2 & 63;
        float wy = ldin(b_W, ch, bf);
#pragma unroll
        for (int ci = 0; ci < kCi; ++ci)
            wy = fmaf(ldin(w_W, (size_t)ch * kCi + ci, bf), y2[q * 33 + br * kCi + ci], wy);
        float inv = rsqrtf(ldin(var, ch, bf) + EPS_BN);
        float z = (wy - ldin(mean, ch, bf)) * (ldin(gamma, ch, bf) * inv) + ldin(beta, ch, bf);
        const void* res = br ? bfimg : x;
        z += ldin(res, ((size_t)b * kC + ch) * kN + q0 + q, bf);
        stout(out, ((size_t)b * 2 * kC + ch2) * kN + q0 + q, z, bf);
    }
}

// ---------------------------------------------------------------------------
extern "C" void kernel_launch(void* const* d_in, const int* in_sizes, int n_in,
                              void* d_out, int out_size, void* d_ws, size_t ws_size,
                              hipStream_t stream)
{
    const void* bfimg   = d_in[0];
    const void* x       = d_in[1];
    const void* w_theta = d_in[2];
    const void* b_theta = d_in[3];
    const void* w_phi   = d_in[4];
    const void* b_phi   = d_in[5];
    const void* w_g     = d_in[6];
    const void* b_g     = d_in[7];
    const void* w_gbf   = d_in[8];
    const void* b_gbf   = d_in[9];
    const void* w_W     = d_in[10];
    const void* b_W     = d_in[11];
    const void* gamma   = d_in[12];
    const void* beta    = d_in[13];
    const void* mean    = d_in[14];
    const void* var     = d_in[15];

    char* base = (char*)d_ws;
    char* th_p = base + 256;                               // 2*6400*32 = 409600
    char* ph_p = th_p + (size_t)kB * kN * THB;             // 2*6400*48 = 614400
    char* gx_p = ph_p + (size_t)kB * kN * PHB;             // 2*200*1024 = 409600
    char* gb_p = gx_p + (size_t)kB * (kN / 32) * SGB;      // 409600

    proj_kernel<<<800, 256, 0, stream>>>(
        bfimg, x, w_theta, b_theta, w_phi, b_phi, w_g, b_g, w_gbf, b_gbf,
        th_p, ph_p, gx_p, gb_p);

    attn_kernel<<<kB * (kN / QT), 512, 0, stream>>>(
        th_p, ph_p, gx_p, gb_p,
        bfimg, x, w_W, b_W, gamma, beta, mean, var, d_out);
}